// Round 3
// baseline (4219.867 us; speedup 1.0000x reference)
//
#include <hip/hip_runtime.h>
#include <hip/hip_bf16.h>

typedef __attribute__((ext_vector_type(8))) short bf16x8;
typedef __attribute__((ext_vector_type(4))) float f32x4;
typedef __attribute__((ext_vector_type(4))) unsigned short u16x4;

static __device__ __forceinline__ unsigned short f2bf(float f) {
  unsigned u = __builtin_bit_cast(unsigned, f);
  u += 0x7FFFu + ((u >> 16) & 1u);
  return (unsigned short)(u >> 16);
}
static __device__ __forceinline__ float bf2f(unsigned short h) {
  unsigned u = ((unsigned)h) << 16;
  return __builtin_bit_cast(float, u);
}
static __device__ __forceinline__ float sigm(float x) {
  return __builtin_amdgcn_rcpf(1.0f + __builtin_amdgcn_exp2f(x * -1.44269504088896f));
}
static __device__ __forceinline__ float tanh_fast(float x) {
  float e = __builtin_amdgcn_exp2f(x * 2.88539008177793f);
  return 1.0f - 2.0f * __builtin_amdgcn_rcpf(1.0f + e);
}

// ---------------------------------------------------------------------------
// Phase 1: xg[m][g] = x[m][:] . w_ih[g][:] + b_ih[g] (+ b_hh[g] for r,z gates)
// m in [0, C*128), g in [0,768), K=256. Output bf16. Tile 128x128, 4 waves.
// ---------------------------------------------------------------------------
__global__ __launch_bounds__(256) void gru_xgates(
    const float* __restrict__ x,     // [C*128][256]
    const float* __restrict__ w_ih,  // [768][256]
    const float* __restrict__ b_ih,  // [768]
    const float* __restrict__ b_hh,  // [768]
    unsigned short* __restrict__ xg) // [C*128][768] bf16
{
  __shared__ unsigned short Al[128][40];  // 80B row stride = 16*5: aligned + 2-way banks
  __shared__ unsigned short Bl[128][40];

  const int t = threadIdx.x;
  const int lane = t & 63;
  const int w = t >> 6;
  const int l15 = lane & 15;
  const int lhi = lane >> 4;
  const int m0 = blockIdx.y * 128;
  const int g0 = blockIdx.x * 128;
  const int wm = (w >> 1) * 64;   // wave's m-offset in tile
  const int wn = (w & 1) * 64;    // wave's n-offset in tile
  const int r_st = t >> 3;        // 0..31
  const int k_st = (t & 7) * 4;   // 0..28

  f32x4 acc[4][4];
  #pragma unroll
  for (int mt = 0; mt < 4; ++mt)
    #pragma unroll
    for (int nt = 0; nt < 4; ++nt) acc[mt][nt] = (f32x4){0.f, 0.f, 0.f, 0.f};

  float bias[4];
  #pragma unroll
  for (int nt = 0; nt < 4; ++nt) {
    const int col = g0 + wn + nt * 16 + l15;
    bias[nt] = b_ih[col] + (col < 512 ? b_hh[col] : 0.f);
  }

  for (int kt = 0; kt < 8; ++kt) {
    const int k0 = kt * 32 + k_st;
    #pragma unroll
    for (int q = 0; q < 4; ++q) {
      const int r = r_st + q * 32;
      float4 a = *(const float4*)(x + (size_t)(m0 + r) * 256 + k0);
      float4 b = *(const float4*)(w_ih + (size_t)(g0 + r) * 256 + k0);
      *(u16x4*)&Al[r][k_st] = (u16x4){f2bf(a.x), f2bf(a.y), f2bf(a.z), f2bf(a.w)};
      *(u16x4*)&Bl[r][k_st] = (u16x4){f2bf(b.x), f2bf(b.y), f2bf(b.z), f2bf(b.w)};
    }
    __syncthreads();

    bf16x8 af[4], bfv[4];
    #pragma unroll
    for (int i = 0; i < 4; ++i) {
      af[i]  = *(const bf16x8*)&Al[wm + i * 16 + l15][lhi * 8];
      bfv[i] = *(const bf16x8*)&Bl[wn + i * 16 + l15][lhi * 8];
    }
    #pragma unroll
    for (int mt = 0; mt < 4; ++mt)
      #pragma unroll
      for (int nt = 0; nt < 4; ++nt)
        acc[mt][nt] = __builtin_amdgcn_mfma_f32_16x16x32_bf16(af[mt], bfv[nt], acc[mt][nt], 0, 0, 0);
    __syncthreads();
  }

  // C layout: row = lhi*4+q (M), col = l15 (N)
  #pragma unroll
  for (int mt = 0; mt < 4; ++mt)
    #pragma unroll
    for (int nt = 0; nt < 4; ++nt)
      #pragma unroll
      for (int q = 0; q < 4; ++q) {
        const int row = m0 + wm + mt * 16 + lhi * 4 + q;
        const int col = g0 + wn + nt * 16 + l15;
        xg[(size_t)row * 768 + col] = f2bf(acc[mt][nt][q] + bias[nt]);
      }
}

// ---------------------------------------------------------------------------
// Phase 2: recurrence over `steps` timesteps. 8 blocks x 16 batch rows,
// 512 threads (8 waves, 2/SIMD -> 256 VGPR cap).
// Swapped MFMA: C[ghcol][batch] = sum_k W_hh[k][ghcol] * h[batch][k].
// A = W_hh bf16 fragments VGPR-resident (wave w owns cols g*256+w*32+[0,32)).
// B = h bf16 from double-buffered XOR-swizzled LDS.
// Thread (w,lane): batch b = lane&15, h-cols c = w*32+half*16+(lane>>4)*4+q.
// Its r/z/n pre-activations land in its own acc regs -> no gh LDS exchange.
// fp32 h truth in regs; xg prefetched one step ahead (non-overlapping ranges).
// ---------------------------------------------------------------------------
__global__ __launch_bounds__(512) void gru_rec(
    const float* __restrict__ hin,         // [128][256] fp32 (h0 or carried state)
    const float* __restrict__ w_hh,        // [256][768] k-major
    const float* __restrict__ b_hh,        // [768]
    const unsigned short* __restrict__ xg, // [steps][128][768] bf16
    float* __restrict__ hstate,            // [128][256] carried state out
    float* __restrict__ out,               // full output base
    int s0, int steps)
{
  __shared__ unsigned short hb[2][4096];   // 2 x [16 rows x 256 cols] bf16, swizzled

  const int t = threadIdx.x;
  const int lane = t & 63;
  const int w = t >> 6;        // 0..7
  const int l15 = lane & 15;
  const int lhi = lane >> 4;   // 0..3
  const int B0 = blockIdx.x * 16;
  const int swz = (l15 & 7) << 4;
  const int cbase = w * 32 + lhi * 4;

  // ---- W_hh fragments: A[m -> col (l15)][k = kt*32 + lhi*8 + e] ----
  bf16x8 wf[8][6];
  #pragma unroll
  for (int nt = 0; nt < 6; ++nt) {
    const int col = (nt >> 1) * 256 + w * 32 + (nt & 1) * 16 + l15;
    #pragma unroll
    for (int kt = 0; kt < 8; ++kt) {
      bf16x8 v;
      #pragma unroll
      for (int e = 0; e < 8; ++e)
        v[e] = (short)f2bf(w_hh[(size_t)(kt * 32 + lhi * 8 + e) * 768 + col]);
      wf[kt][nt] = v;
    }
  }

  // n-gate bias as bf16 (r/z biases folded into xg by phase 1)
  u16x4 biasn[2];
  #pragma unroll
  for (int half = 0; half < 2; ++half) {
    f32x4 bv = *(const f32x4*)(b_hh + 512 + cbase + half * 16);
    biasn[half] = (u16x4){f2bf(bv[0]), f2bf(bv[1]), f2bf(bv[2]), f2bf(bv[3])};
  }

  // ---- h state (fp32 regs) + bf16 copy into LDS buf 0 ----
  f32x4 hp[2];
  #pragma unroll
  for (int half = 0; half < 2; ++half) {
    hp[half] = *(const f32x4*)(hin + (size_t)(B0 + l15) * 256 + cbase + half * 16);
    const int off = l15 * 512 + (((cbase + half * 16) * 2) ^ swz);
    *(u16x4*)((char*)hb[0] + off) =
        (u16x4){f2bf(hp[half][0]), f2bf(hp[half][1]), f2bf(hp[half][2]), f2bf(hp[half][3])};
  }

  // ---- xg for step 0 (prefetched; consumed at end of each step) ----
  const unsigned short* xp = xg + (size_t)(B0 + l15) * 768 + cbase;
  u16x4 xgv[6];
  #pragma unroll
  for (int g = 0; g < 3; ++g)
    #pragma unroll
    for (int half = 0; half < 2; ++half)
      xgv[g * 2 + half] = *(const u16x4*)(xp + g * 256 + half * 16);

  float* op = out + (size_t)(B0 + l15) * 256 + cbase;
  __syncthreads();

  #pragma unroll 1
  for (int s = 0; s < steps; ++s) {
    const char* hcur = (const char*)hb[s & 1];
    char* hnxt = (char*)hb[(s & 1) ^ 1];

    f32x4 acc[6];
    acc[0] = acc[1] = acc[2] = acc[3] = (f32x4){0.f, 0.f, 0.f, 0.f};
    acc[4] = (f32x4){bf2f(biasn[0][0]), bf2f(biasn[0][1]), bf2f(biasn[0][2]), bf2f(biasn[0][3])};
    acc[5] = (f32x4){bf2f(biasn[1][0]), bf2f(biasn[1][1]), bf2f(biasn[1][2]), bf2f(biasn[1][3])};

    #pragma unroll
    for (int kt = 0; kt < 8; ++kt) {
      bf16x8 hf = *(const bf16x8*)(hcur + l15 * 512 + ((kt * 64 + lhi * 16) ^ swz));
      #pragma unroll
      for (int nt = 0; nt < 6; ++nt)
        acc[nt] = __builtin_amdgcn_mfma_f32_16x16x32_bf16(wf[kt][nt], hf, acc[nt], 0, 0, 0);
    }

    #pragma unroll
    for (int half = 0; half < 2; ++half) {
      f32x4 hn;
      #pragma unroll
      for (int q = 0; q < 4; ++q) {
        const float r = sigm(bf2f(xgv[half][q]) + acc[half][q]);
        const float z = sigm(bf2f(xgv[2 + half][q]) + acc[2 + half][q]);
        const float n = tanh_fast(bf2f(xgv[4 + half][q]) + r * acc[4 + half][q]);
        hn[q] = n + z * (hp[half][q] - n);
      }
      hp[half] = hn;
      const int off = l15 * 512 + (((cbase + half * 16) * 2) ^ swz);
      *(u16x4*)(hnxt + off) =
          (u16x4){f2bf(hn[0]), f2bf(hn[1]), f2bf(hn[2]), f2bf(hn[3])};
      *(f32x4*)(op + (size_t)(s0 + s) * 32768 + half * 16) = hn;
    }

    // prefetch xg for next step; consumed at end of next step (full-step latency cover)
    xp += (s + 1 < steps) ? 98304 : 0;
    #pragma unroll
    for (int g = 0; g < 3; ++g)
      #pragma unroll
      for (int half = 0; half < 2; ++half)
        xgv[g * 2 + half] = *(const u16x4*)(xp + g * 256 + half * 16);

    __syncthreads();
  }

  // carried state + h_final region (last chunk's write wins)
  #pragma unroll
  for (int half = 0; half < 2; ++half) {
    *(f32x4*)(hstate + (size_t)(B0 + l15) * 256 + cbase + half * 16) = hp[half];
    *(f32x4*)(op + (size_t)1024 * 32768 + half * 16) = hp[half];
  }
}

// ---------------------------------------------------------------------------
extern "C" void kernel_launch(void* const* d_in, const int* in_sizes, int n_in,
                              void* d_out, int out_size, void* d_ws, size_t ws_size,
                              hipStream_t stream) {
  const float* x    = (const float*)d_in[0];  // [1024][128][256]
  const float* h0   = (const float*)d_in[1];  // [128][256]
  const float* w_ih = (const float*)d_in[2];  // [768][256]
  const float* w_hh = (const float*)d_in[3];  // [256][768]
  const float* b_ih = (const float*)d_in[4];  // [768]
  const float* b_hh = (const float*)d_in[5];  // [768]
  float* out = (float*)d_out;

  // ws layout: [0,128KB) carried h state fp32; rest = xg chunk buffer (bf16).
  float* hstate = (float*)d_ws;
  unsigned short* xg = (unsigned short*)((char*)d_ws + 131072);
  const size_t avail = ws_size > 131072 ? ws_size - 131072 : 0;

  // chunk steps C: largest power of two with C*128*768*2 bytes fitting in ws
  int C = 1024;
  while (C > 1 && (size_t)C * 196608ull > avail) C >>= 1;

  for (int c0 = 0; c0 < 1024; c0 += C) {
    gru_xgates<<<dim3(6, C), 256, 0, stream>>>(x + (size_t)c0 * 32768, w_ih, b_ih, b_hh, xg);
    gru_rec<<<dim3(8), 512, 0, stream>>>(c0 == 0 ? h0 : hstate, w_hh, b_hh, xg,
                                         hstate, out, c0, C);
  }
}

// Round 4
// 3649.700 us; speedup vs baseline: 1.1562x; 1.1562x over previous
//
#include <hip/hip_runtime.h>
#include <hip/hip_bf16.h>

typedef __attribute__((ext_vector_type(8))) short bf16x8;
typedef __attribute__((ext_vector_type(4))) float f32x4;
typedef __attribute__((ext_vector_type(4))) unsigned short u16x4;

static __device__ __forceinline__ unsigned short f2bf(float f) {
  unsigned u = __builtin_bit_cast(unsigned, f);
  u += 0x7FFFu + ((u >> 16) & 1u);
  return (unsigned short)(u >> 16);
}
static __device__ __forceinline__ float bf2f(unsigned short h) {
  unsigned u = ((unsigned)h) << 16;
  return __builtin_bit_cast(float, u);
}
static __device__ __forceinline__ float sigm(float x) {
  return __builtin_amdgcn_rcpf(1.0f + __builtin_amdgcn_exp2f(x * -1.44269504088896f));
}
static __device__ __forceinline__ float tanh_fast(float x) {
  float e = __builtin_amdgcn_exp2f(x * 2.88539008177793f);
  return 1.0f - 2.0f * __builtin_amdgcn_rcpf(1.0f + e);
}

// ---------------------------------------------------------------------------
// Phase 1: xg[m][g] = x[m][:] . w_ih[g][:] + b_ih[g] (+ b_hh[g] for r,z gates)
// Tile 128m x 256n, K=256, 4 waves (each 64m x 128n). Output bf16.
// Grid (3, C): x re-read only 3x (was 6x).
// ---------------------------------------------------------------------------
__global__ __launch_bounds__(256, 2) void gru_xgates(
    const float* __restrict__ x,     // [C*128][256]
    const float* __restrict__ w_ih,  // [768][256]
    const float* __restrict__ b_ih,  // [768]
    const float* __restrict__ b_hh,  // [768]
    unsigned short* __restrict__ xg) // [C*128][768] bf16
{
  __shared__ unsigned short Al[128][40];  // 80B row stride
  __shared__ unsigned short Bl[256][40];

  const int t = threadIdx.x;
  const int lane = t & 63;
  const int w = t >> 6;
  const int l15 = lane & 15;
  const int lhi = lane >> 4;
  const int m0 = blockIdx.y * 128;
  const int g0 = blockIdx.x * 256;
  const int wm = (w >> 1) * 64;
  const int wn = (w & 1) * 128;
  const int rA = t >> 1;          // 0..127
  const int kq = (t & 1) * 16;    // 0 or 16

  f32x4 acc[4][8];
  #pragma unroll
  for (int mt = 0; mt < 4; ++mt)
    #pragma unroll
    for (int nt = 0; nt < 8; ++nt) acc[mt][nt] = (f32x4){0.f, 0.f, 0.f, 0.f};

  float bias[8];
  #pragma unroll
  for (int nt = 0; nt < 8; ++nt) {
    const int col = g0 + wn + nt * 16 + l15;
    bias[nt] = b_ih[col] + (col < 512 ? b_hh[col] : 0.f);
  }

  for (int kt = 0; kt < 8; ++kt) {
    const int k0 = kt * 32 + kq;
    #pragma unroll
    for (int i = 0; i < 4; ++i) {
      float4 a = *(const float4*)(x + (size_t)(m0 + rA) * 256 + k0 + i * 4);
      *(u16x4*)&Al[rA][kq + i * 4] = (u16x4){f2bf(a.x), f2bf(a.y), f2bf(a.z), f2bf(a.w)};
    }
    #pragma unroll
    for (int h2 = 0; h2 < 2; ++h2) {
      const int rB = rA + h2 * 128;
      #pragma unroll
      for (int i = 0; i < 4; ++i) {
        float4 b = *(const float4*)(w_ih + (size_t)(g0 + rB) * 256 + k0 + i * 4);
        *(u16x4*)&Bl[rB][kq + i * 4] = (u16x4){f2bf(b.x), f2bf(b.y), f2bf(b.z), f2bf(b.w)};
      }
    }
    __syncthreads();

    bf16x8 af[4], bfv[8];
    #pragma unroll
    for (int i = 0; i < 4; ++i) af[i] = *(const bf16x8*)&Al[wm + i * 16 + l15][lhi * 8];
    #pragma unroll
    for (int nt = 0; nt < 8; ++nt) bfv[nt] = *(const bf16x8*)&Bl[wn + nt * 16 + l15][lhi * 8];
    #pragma unroll
    for (int mt = 0; mt < 4; ++mt)
      #pragma unroll
      for (int nt = 0; nt < 8; ++nt)
        acc[mt][nt] = __builtin_amdgcn_mfma_f32_16x16x32_bf16(af[mt], bfv[nt], acc[mt][nt], 0, 0, 0);
    __syncthreads();
  }

  #pragma unroll
  for (int mt = 0; mt < 4; ++mt)
    #pragma unroll
    for (int nt = 0; nt < 8; ++nt)
      #pragma unroll
      for (int q = 0; q < 4; ++q) {
        const int row = m0 + wm + mt * 16 + lhi * 4 + q;
        const int col = g0 + wn + nt * 16 + l15;
        xg[(size_t)row * 768 + col] = f2bf(acc[mt][nt][q] + bias[nt]);
      }
}

// ---------------------------------------------------------------------------
// Phase 2: recurrence. 8 blocks x 16 batch rows, 512 threads (8 waves).
// __launch_bounds__(512,2) -> 256 VGPR cap; register plan ~245:
//   wf 192 + acc 24 + xgv 12 + temps. fp32 h truth and n-bias live in LDS.
// Swapped MFMA: C[ghcol][batch] = sum_k W_hh[k][ghcol] * h[batch][k].
// Thread (w,lane): batch b = lane&15, h-cols c = w*32 + half*16 + (lane>>4)*4+q.
// ---------------------------------------------------------------------------
__global__ __launch_bounds__(512, 2) void gru_rec(
    const float* __restrict__ hin,         // [128][256] fp32
    const float* __restrict__ w_hh,        // [256][768] k-major
    const float* __restrict__ b_hh,        // [768]
    const unsigned short* __restrict__ xg, // [steps][128][768] bf16
    float* __restrict__ hstate,            // [128][256] carried state out
    float* __restrict__ out,               // full output base
    int s0, int steps)
{
  __shared__ unsigned short hb[2][4096];   // bf16 h, double-buffered, XOR-swizzled
  __shared__ float hpf[16][256];           // fp32 h truth (per-thread-owned slots)
  __shared__ float bias_lds[256];          // n-gate b_hh

  const int t = threadIdx.x;
  const int lane = t & 63;
  const int w = t >> 6;        // 0..7
  const int l15 = lane & 15;
  const int lhi = lane >> 4;   // 0..3
  const int B0 = blockIdx.x * 16;
  const int swz = (l15 & 7) << 4;
  const int cbase = w * 32 + lhi * 4;

  // ---- W_hh fragments: A[m -> col (l15)][k = kt*32 + lhi*8 + e] ----
  bf16x8 wf[8][6];
  #pragma unroll
  for (int nt = 0; nt < 6; ++nt) {
    const int col = (nt >> 1) * 256 + w * 32 + (nt & 1) * 16 + l15;
    #pragma unroll
    for (int kt = 0; kt < 8; ++kt) {
      bf16x8 v;
      #pragma unroll
      for (int e = 0; e < 8; ++e)
        v[e] = (short)f2bf(w_hh[(size_t)(kt * 32 + lhi * 8 + e) * 768 + col]);
      wf[kt][nt] = v;
    }
  }

  if (t < 256) bias_lds[t] = b_hh[512 + t];

  // ---- h state init: fp32 -> LDS truth + bf16 swizzled copy (buf 0) ----
  #pragma unroll
  for (int half = 0; half < 2; ++half) {
    const int c = cbase + half * 16;
    f32x4 h = *(const f32x4*)(hin + (size_t)(B0 + l15) * 256 + c);
    *(f32x4*)((char*)hpf + l15 * 1024 + ((c * 4) ^ swz)) = h;
    *(u16x4*)((char*)hb[0] + l15 * 512 + ((c * 2) ^ swz)) =
        (u16x4){f2bf(h[0]), f2bf(h[1]), f2bf(h[2]), f2bf(h[3])};
  }

  // ---- xg for step 0 ----
  const unsigned short* xp = xg + (size_t)(B0 + l15) * 768 + cbase;
  u16x4 xgv[6];
  #pragma unroll
  for (int g = 0; g < 3; ++g)
    #pragma unroll
    for (int half = 0; half < 2; ++half)
      xgv[g * 2 + half] = *(const u16x4*)(xp + g * 256 + half * 16);

  float* op = out + (size_t)s0 * 32768 + (size_t)(B0 + l15) * 256 + cbase;
  __syncthreads();

  #pragma unroll 1
  for (int s = 0; s < steps; ++s) {
    const char* hcur = (const char*)hb[s & 1];
    char* hnxt = (char*)hb[(s & 1) ^ 1];

    f32x4 acc[6];
    acc[0] = acc[1] = acc[2] = acc[3] = (f32x4){0.f, 0.f, 0.f, 0.f};
    acc[4] = *(const f32x4*)&bias_lds[cbase];
    acc[5] = *(const f32x4*)&bias_lds[cbase + 16];

    #pragma unroll
    for (int kt = 0; kt < 8; ++kt) {
      bf16x8 hf = *(const bf16x8*)(hcur + l15 * 512 + ((kt * 64 + lhi * 16) ^ swz));
      #pragma unroll
      for (int nt = 0; nt < 6; ++nt)
        acc[nt] = __builtin_amdgcn_mfma_f32_16x16x32_bf16(wf[kt][nt], hf, acc[nt], 0, 0, 0);
    }

    // next step's xg base (clamped on last step)
    const unsigned short* xpn = xp + (s + 1 < steps ? 98304 : 0);

    #pragma unroll
    for (int half = 0; half < 2; ++half) {
      const int c = cbase + half * 16;
      f32x4 hp = *(const f32x4*)((const char*)hpf + l15 * 1024 + ((c * 4) ^ swz));
      f32x4 hn;
      #pragma unroll
      for (int q = 0; q < 4; ++q) {
        const float r = sigm(bf2f(xgv[half][q]) + acc[half][q]);
        const float z = sigm(bf2f(xgv[2 + half][q]) + acc[2 + half][q]);
        const float n = tanh_fast(bf2f(xgv[4 + half][q]) + r * acc[4 + half][q]);
        hn[q] = n + z * (hp[q] - n);
      }
      // reload the consumed xgv pieces for the next step (issues ~200cyc pre-barrier)
      xgv[half]     = *(const u16x4*)(xpn + half * 16);
      xgv[2 + half] = *(const u16x4*)(xpn + 256 + half * 16);
      xgv[4 + half] = *(const u16x4*)(xpn + 512 + half * 16);

      *(f32x4*)((char*)hpf + l15 * 1024 + ((c * 4) ^ swz)) = hn;
      *(u16x4*)(hnxt + l15 * 512 + ((c * 2) ^ swz)) =
          (u16x4){f2bf(hn[0]), f2bf(hn[1]), f2bf(hn[2]), f2bf(hn[3])};
      *(f32x4*)(op + half * 16) = hn;
    }

    xp = xpn;
    op += 32768;
    __syncthreads();
  }

  // carried state + h_final region (last chunk's write wins)
  #pragma unroll
  for (int half = 0; half < 2; ++half) {
    const int c = cbase + half * 16;
    f32x4 h = *(const f32x4*)((const char*)hpf + l15 * 1024 + ((c * 4) ^ swz));
    *(f32x4*)(hstate + (size_t)(B0 + l15) * 256 + c) = h;
    *(f32x4*)(out + (size_t)1024 * 32768 + (size_t)(B0 + l15) * 256 + c) = h;
  }
}

// ---------------------------------------------------------------------------
extern "C" void kernel_launch(void* const* d_in, const int* in_sizes, int n_in,
                              void* d_out, int out_size, void* d_ws, size_t ws_size,
                              hipStream_t stream) {
  const float* x    = (const float*)d_in[0];  // [1024][128][256]
  const float* h0   = (const float*)d_in[1];  // [128][256]
  const float* w_ih = (const float*)d_in[2];  // [768][256]
  const float* w_hh = (const float*)d_in[3];  // [256][768]
  const float* b_ih = (const float*)d_in[4];  // [768]
  const float* b_hh = (const float*)d_in[5];  // [768]
  float* out = (float*)d_out;

  // ws layout: [0,128KB) carried h state fp32; rest = xg chunk buffer (bf16).
  float* hstate = (float*)d_ws;
  unsigned short* xg = (unsigned short*)((char*)d_ws + 131072);
  const size_t avail = ws_size > 131072 ? ws_size - 131072 : 0;

  int C = 1024;
  while (C > 1 && (size_t)C * 196608ull > avail) C >>= 1;

  for (int c0 = 0; c0 < 1024; c0 += C) {
    gru_xgates<<<dim3(3, C), 256, 0, stream>>>(x + (size_t)c0 * 32768, w_ih, b_ih, b_hh, xg);
    gru_rec<<<dim3(8), 512, 0, stream>>>(c0 == 0 ? h0 : hstate, w_hh, b_hh, xg,
                                         hstate, out, c0, C);
  }
}

// Round 5
// 3636.388 us; speedup vs baseline: 1.1605x; 1.0037x over previous
//
#include <hip/hip_runtime.h>
#include <hip/hip_bf16.h>

typedef __attribute__((ext_vector_type(8))) short bf16x8;
typedef __attribute__((ext_vector_type(4))) float f32x4;
typedef __attribute__((ext_vector_type(4))) unsigned short u16x4;

static __device__ __forceinline__ unsigned short f2bf(float f) {
  unsigned u = __builtin_bit_cast(unsigned, f);
  u += 0x7FFFu + ((u >> 16) & 1u);
  return (unsigned short)(u >> 16);
}
static __device__ __forceinline__ float bf2f(unsigned short h) {
  unsigned u = ((unsigned)h) << 16;
  return __builtin_bit_cast(float, u);
}
static __device__ __forceinline__ float sigm(float x) {
  return __builtin_amdgcn_rcpf(1.0f + __builtin_amdgcn_exp2f(x * -1.44269504088896f));
}
static __device__ __forceinline__ float tanh_fast(float x) {
  float e = __builtin_amdgcn_exp2f(x * 2.88539008177793f);
  return 1.0f - 2.0f * __builtin_amdgcn_rcpf(1.0f + e);
}

// ---------------------------------------------------------------------------
// Phase 1: xg[m][g] = x[m][:] . w_ih[g][:] + b_ih[g] (+ b_hh[g] for r,z gates)
// Tile 128m x 256n, K=256, 4 waves. Output bf16. (unchanged from round 4)
// ---------------------------------------------------------------------------
__global__ __launch_bounds__(256, 2) void gru_xgates(
    const float* __restrict__ x,     // [C*128][256]
    const float* __restrict__ w_ih,  // [768][256]
    const float* __restrict__ b_ih,  // [768]
    const float* __restrict__ b_hh,  // [768]
    unsigned short* __restrict__ xg) // [C*128][768] bf16
{
  __shared__ unsigned short Al[128][40];
  __shared__ unsigned short Bl[256][40];

  const int t = threadIdx.x;
  const int lane = t & 63;
  const int w = t >> 6;
  const int l15 = lane & 15;
  const int lhi = lane >> 4;
  const int m0 = blockIdx.y * 128;
  const int g0 = blockIdx.x * 256;
  const int wm = (w >> 1) * 64;
  const int wn = (w & 1) * 128;
  const int rA = t >> 1;
  const int kq = (t & 1) * 16;

  f32x4 acc[4][8];
  #pragma unroll
  for (int mt = 0; mt < 4; ++mt)
    #pragma unroll
    for (int nt = 0; nt < 8; ++nt) acc[mt][nt] = (f32x4){0.f, 0.f, 0.f, 0.f};

  float bias[8];
  #pragma unroll
  for (int nt = 0; nt < 8; ++nt) {
    const int col = g0 + wn + nt * 16 + l15;
    bias[nt] = b_ih[col] + (col < 512 ? b_hh[col] : 0.f);
  }

  for (int kt = 0; kt < 8; ++kt) {
    const int k0 = kt * 32 + kq;
    #pragma unroll
    for (int i = 0; i < 4; ++i) {
      float4 a = *(const float4*)(x + (size_t)(m0 + rA) * 256 + k0 + i * 4);
      *(u16x4*)&Al[rA][kq + i * 4] = (u16x4){f2bf(a.x), f2bf(a.y), f2bf(a.z), f2bf(a.w)};
    }
    #pragma unroll
    for (int h2 = 0; h2 < 2; ++h2) {
      const int rB = rA + h2 * 128;
      #pragma unroll
      for (int i = 0; i < 4; ++i) {
        float4 b = *(const float4*)(w_ih + (size_t)(g0 + rB) * 256 + k0 + i * 4);
        *(u16x4*)&Bl[rB][kq + i * 4] = (u16x4){f2bf(b.x), f2bf(b.y), f2bf(b.z), f2bf(b.w)};
      }
    }
    __syncthreads();

    bf16x8 af[4], bfv[8];
    #pragma unroll
    for (int i = 0; i < 4; ++i) af[i] = *(const bf16x8*)&Al[wm + i * 16 + l15][lhi * 8];
    #pragma unroll
    for (int nt = 0; nt < 8; ++nt) bfv[nt] = *(const bf16x8*)&Bl[wn + nt * 16 + l15][lhi * 8];
    #pragma unroll
    for (int mt = 0; mt < 4; ++mt)
      #pragma unroll
      for (int nt = 0; nt < 8; ++nt)
        acc[mt][nt] = __builtin_amdgcn_mfma_f32_16x16x32_bf16(af[mt], bfv[nt], acc[mt][nt], 0, 0, 0);
    __syncthreads();
  }

  #pragma unroll
  for (int mt = 0; mt < 4; ++mt)
    #pragma unroll
    for (int nt = 0; nt < 8; ++nt)
      #pragma unroll
      for (int q = 0; q < 4; ++q) {
        const int row = m0 + wm + mt * 16 + lhi * 4 + q;
        const int col = g0 + wn + nt * 16 + l15;
        xg[(size_t)row * 768 + col] = f2bf(acc[mt][nt][q] + bias[nt]);
      }
}

// ---------------------------------------------------------------------------
// Phase 2: recurrence. 8 blocks x 16 batch rows, 512 threads (8 waves).
// Swapped MFMA: C[ghcol][batch] = sum_k W_hh[k][ghcol] * h[batch][k].
// A = W_hh bf16 fragments VGPR-resident; B = h bf16 from LDS.
//
// hb layout (bank-bijective, dword-granular): element pair kp=k>>1 of batch b
//   dword index = (kp>>1)*32 + ((b + 16*(kp&1) + 4*((kp>>1)&1) + 8*((kp>>2)&3)) & 31)
// -> every ds_read_b32 / ds_write_b32 instruction hits each bank exactly 2x
//    (2-way = free, m136), and the mapping is bijective (no collisions).
// r/z xg folded into MFMA C-init (loads consumed at step top -> no barrier-
// drain stall); n-gate xg double-buffered in regs.
// ---------------------------------------------------------------------------
__global__ __launch_bounds__(512, 2) void gru_rec(
    const float* __restrict__ hin,         // [128][256] fp32
    const float* __restrict__ w_hh,        // [256][768] k-major
    const float* __restrict__ b_hh,        // [768]
    const unsigned short* __restrict__ xg, // [steps][128][768] bf16
    float* __restrict__ hstate,            // [128][256] carried state out
    float* __restrict__ out,               // full output base
    int s0, int steps)
{
  __shared__ unsigned hb[2][2048];         // 2 x 8KB dword-interleaved bf16 h
  __shared__ float bias_lds[256];          // n-gate b_hh

  const int t = threadIdx.x;
  const int lane = t & 63;
  const int w = t >> 6;        // 0..7
  const int l15 = lane & 15;
  const int lhi = lane >> 4;   // 0..3
  const int B0 = blockIdx.x * 16;
  const int cbase = w * 32 + lhi * 4;

  // ---- W_hh fragments: A[m -> ghcol (l15)][k = kt*32 + lhi*8 + e] ----
  bf16x8 wf[8][6];
  #pragma unroll
  for (int nt = 0; nt < 6; ++nt) {
    const int col = (nt >> 1) * 256 + w * 32 + (nt & 1) * 16 + l15;
    #pragma unroll
    for (int kt = 0; kt < 8; ++kt) {
      bf16x8 v;
      #pragma unroll
      for (int e = 0; e < 8; ++e)
        v[e] = (short)f2bf(w_hh[(size_t)(kt * 32 + lhi * 8 + e) * 768 + col]);
      wf[kt][nt] = v;
    }
  }

  if (t < 256) bias_lds[t] = b_hh[512 + t];

  // ---- LDS byte-offset tables (within one 8KB buffer) ----
  int rb[4];                                  // read: j=0..3, kp = kt*16+lhi*4+j
  #pragma unroll
  for (int j = 0; j < 4; ++j) {
    const int row = lhi * 2 + (j >> 1);
    const int slot = (l15 + 16 * (j & 1) + 4 * (j >> 1) + 8 * lhi) & 31;
    rb[j] = (row * 32 + slot) * 4;
  }
  int wb[2][2];                               // write: [half][kp parity]
  #pragma unroll
  for (int half = 0; half < 2; ++half) {
    const int row = w * 8 + lhi + half * 4;
    const int sl0 = (l15 + 4 * (lhi & 1) + 8 * (((lhi >> 1) + half * 2) & 3)) & 31;
    wb[half][0] = (row * 32 + sl0) * 4;
    wb[half][1] = (row * 32 + ((sl0 + 16) & 31)) * 4;
  }

  // ---- h state init (fp32 regs) + bf16 interleaved copy into buf 0 ----
  f32x4 hp[2];
  {
    char* hw = (char*)hb[0];
    #pragma unroll
    for (int half = 0; half < 2; ++half) {
      hp[half] = *(const f32x4*)(hin + (size_t)(B0 + l15) * 256 + cbase + half * 16);
      unsigned d0 = (unsigned)f2bf(hp[half][0]) | ((unsigned)f2bf(hp[half][1]) << 16);
      unsigned d1 = (unsigned)f2bf(hp[half][2]) | ((unsigned)f2bf(hp[half][3]) << 16);
      *(unsigned*)(hw + wb[half][0]) = d0;
      *(unsigned*)(hw + wb[half][1]) = d1;
    }
  }

  // ---- xg for step 0 ----
  const unsigned short* xp = xg + (size_t)(B0 + l15) * 768 + cbase;
  u16x4 xrz[4];    // r: [0]=half0 [1]=half1 ; z: [2],[3]   (single-buffered)
  u16x4 xn_c[2], xn_n[2];  // n-gate, ping-pong
  #pragma unroll
  for (int half = 0; half < 2; ++half) {
    xrz[half]     = *(const u16x4*)(xp + half * 16);
    xrz[2 + half] = *(const u16x4*)(xp + 256 + half * 16);
    xn_c[half]    = *(const u16x4*)(xp + 512 + half * 16);
  }

  float* op = out + (size_t)s0 * 32768 + (size_t)(B0 + l15) * 256 + cbase;
  __syncthreads();

  #pragma unroll 1
  for (int s = 0; s < steps; ++s) {
    const char* hr = (const char*)hb[s & 1];
    char* hw = (char*)hb[(s & 1) ^ 1];

    // ---- acc init: r/z seeded with xg (consumes xrz now), n with bias ----
    f32x4 acc[6];
    #pragma unroll
    for (int half = 0; half < 2; ++half) {
      acc[half]     = (f32x4){bf2f(xrz[half][0]), bf2f(xrz[half][1]),
                              bf2f(xrz[half][2]), bf2f(xrz[half][3])};
      acc[2 + half] = (f32x4){bf2f(xrz[2 + half][0]), bf2f(xrz[2 + half][1]),
                              bf2f(xrz[2 + half][2]), bf2f(xrz[2 + half][3])};
      acc[4 + half] = *(const f32x4*)&bias_lds[cbase + half * 16];
    }

    // ---- prefetch next step's xg (long latency cover: whole step) ----
    const unsigned short* xpn = xp + (s + 1 < steps ? 98304 : 0);
    #pragma unroll
    for (int half = 0; half < 2; ++half) {
      xrz[half]     = *(const u16x4*)(xpn + half * 16);
      xrz[2 + half] = *(const u16x4*)(xpn + 256 + half * 16);
      xn_n[half]    = *(const u16x4*)(xpn + 512 + half * 16);
    }

    // ---- gh += W_hh . h ----
    #pragma unroll
    for (int kt = 0; kt < 8; ++kt) {
      int4 hd;
      hd.x = *(const int*)(hr + rb[0] + kt * 1024);
      hd.y = *(const int*)(hr + rb[1] + kt * 1024);
      hd.z = *(const int*)(hr + rb[2] + kt * 1024);
      hd.w = *(const int*)(hr + rb[3] + kt * 1024);
      const bf16x8 hf = __builtin_bit_cast(bf16x8, hd);
      #pragma unroll
      for (int nt = 0; nt < 6; ++nt)
        acc[nt] = __builtin_amdgcn_mfma_f32_16x16x32_bf16(wf[kt][nt], hf, acc[nt], 0, 0, 0);
    }

    // ---- gates ----
    #pragma unroll
    for (int half = 0; half < 2; ++half) {
      f32x4 hn;
      #pragma unroll
      for (int q = 0; q < 4; ++q) {
        const float r = sigm(acc[half][q]);
        const float z = sigm(acc[2 + half][q]);
        const float n = tanh_fast(bf2f(xn_c[half][q]) + r * acc[4 + half][q]);
        hn[q] = n + z * (hp[half][q] - n);
      }
      hp[half] = hn;
      unsigned d0 = (unsigned)f2bf(hn[0]) | ((unsigned)f2bf(hn[1]) << 16);
      unsigned d1 = (unsigned)f2bf(hn[2]) | ((unsigned)f2bf(hn[3]) << 16);
      *(unsigned*)(hw + wb[half][0]) = d0;
      *(unsigned*)(hw + wb[half][1]) = d1;
      *(f32x4*)(op + half * 16) = hn;
    }
    xn_c[0] = xn_n[0];
    xn_c[1] = xn_n[1];

    xp = xpn;
    op += 32768;
    __syncthreads();
  }

  // ---- carried state + h_final ----
  #pragma unroll
  for (int half = 0; half < 2; ++half) {
    const int c = cbase + half * 16;
    *(f32x4*)(hstate + (size_t)(B0 + l15) * 256 + c) = hp[half];
    *(f32x4*)(out + (size_t)1024 * 32768 + (size_t)(B0 + l15) * 256 + c) = hp[half];
  }
}

// ---------------------------------------------------------------------------
extern "C" void kernel_launch(void* const* d_in, const int* in_sizes, int n_in,
                              void* d_out, int out_size, void* d_ws, size_t ws_size,
                              hipStream_t stream) {
  const float* x    = (const float*)d_in[0];  // [1024][128][256]
  const float* h0   = (const float*)d_in[1];  // [128][256]
  const float* w_ih = (const float*)d_in[2];  // [768][256]
  const float* w_hh = (const float*)d_in[3];  // [256][768]
  const float* b_ih = (const float*)d_in[4];  // [768]
  const float* b_hh = (const float*)d_in[5];  // [768]
  float* out = (float*)d_out;

  // ws layout: [0,128KB) carried h state fp32; rest = xg chunk buffer (bf16).
  float* hstate = (float*)d_ws;
  unsigned short* xg = (unsigned short*)((char*)d_ws + 131072);
  const size_t avail = ws_size > 131072 ? ws_size - 131072 : 0;

  int C = 1024;
  while (C > 1 && (size_t)C * 196608ull > avail) C >>= 1;

  for (int c0 = 0; c0 < 1024; c0 += C) {
    gru_xgates<<<dim3(3, C), 256, 0, stream>>>(x + (size_t)c0 * 32768, w_ih, b_ih, b_hh, xg);
    gru_rec<<<dim3(8), 512, 0, stream>>>(c0 == 0 ? h0 : hstate, w_hh, b_hh, xg,
                                         hstate, out, c0, C);
  }
}